// Round 10
// baseline (930.001 us; speedup 1.0000x reference)
//
#include <hip/hip_runtime.h>

#define N_NODES 100000
#define N_EDGES 1600000
#define HID 128
#define N_LAYERS 4
#define EPSV 1e-5f
#define NBUCK 1024
#define BSHIFT 7      // 128 nodes per bucket
#define CBLK 4096     // edges per scatter block
#define LSTR 40       // LDS row stride in shorts (80B: 16B-aligned, 2-way-max bank conflicts = free)

using f32x4 = __attribute__((ext_vector_type(4))) float;
using s16x8 = __attribute__((ext_vector_type(8))) short;

__device__ __forceinline__ unsigned short f2bf(float f) {
  union { float f; unsigned u; } c{f};
  unsigned u = c.u;
  return (unsigned short)((u + 0x7fffu + ((u >> 16) & 1u)) >> 16);
}
__device__ __forceinline__ float bf2f(unsigned short s) {
  union { unsigned u; float f; } c{(unsigned)s << 16};
  return c.f;
}

// ---------------- Pass A: bucket histogram (LDS) + deg_out atomics ----------------
__global__ __launch_bounds__(256) void k_hist(const int* __restrict__ src, const int* __restrict__ dst,
                                              int* __restrict__ bucket_cnt, int* __restrict__ deg_out) {
  __shared__ int h[NBUCK];
  for (int i = threadIdx.x; i < NBUCK; i += 256) h[i] = 0;
  __syncthreads();
  int per = (N_EDGES + gridDim.x - 1) / gridDim.x;
  int lo = blockIdx.x * per;
  int hi = lo + per; if (hi > N_EDGES) hi = N_EDGES;
  for (int i = lo + threadIdx.x; i < hi; i += 256) {
    atomicAdd(&h[dst[i] >> BSHIFT], 1);
    atomicAdd(&deg_out[src[i]], 1);
  }
  __syncthreads();
  for (int i = threadIdx.x; i < NBUCK; i += 256)
    if (h[i]) atomicAdd(&bucket_cnt[i], h[i]);
}

// ---------------- Pass B: scan 1024 bucket counts; zero bucket_fill ----------------
__global__ __launch_bounds__(256) void k_bscan(const int* __restrict__ cnt, int* __restrict__ base,
                                               int* __restrict__ fill) {
  __shared__ int wsum[4];
  int tid = threadIdx.x;
  int4 v = *(const int4*)(cnt + tid * 4);
  int s4 = v.x + v.y + v.z + v.w;
  int lane = tid & 63, wid = tid >> 6;
  int sc = s4;
#pragma unroll
  for (int off = 1; off < 64; off <<= 1) {
    int u = __shfl_up(sc, off, 64);
    if (lane >= off) sc += u;
  }
  if (lane == 63) wsum[wid] = sc;
  __syncthreads();
  int woff = 0;
#pragma unroll
  for (int w = 0; w < 4; ++w) woff += (w < wid) ? wsum[w] : 0;
  int excl = woff + sc - s4;
  int4 o;
  o.x = excl; o.y = o.x + v.x; o.z = o.y + v.y; o.w = o.z + v.z;
  *(int4*)(base + tid * 4) = o;
  *(int4*)(fill + tid * 4) = make_int4(0, 0, 0, 0);
  if (tid == 255) base[NBUCK] = woff + sc;  // == N_EDGES
}

// ---------------- Pass C: block-local staged scatter (coalesced, no serialization) ----------------
__global__ __launch_bounds__(256) void k_scatter2(const int* __restrict__ src, const int* __restrict__ dst,
                                                  const int* __restrict__ bucket_base, int* __restrict__ bucket_fill,
                                                  int2* __restrict__ pairs) {
  __shared__ int hist[NBUCK];
  __shared__ int loff[NBUCK];
  __shared__ int gbase_s[NBUCK];
  __shared__ int lcur[NBUCK];
  __shared__ int wsum[4];
  __shared__ int2 stage[CBLK];                 // 32 KB
  __shared__ unsigned short sbuck[CBLK];       // 8 KB
  int tid = threadIdx.x;
  int e0 = blockIdx.x * CBLK;
  int e1 = e0 + CBLK; if (e1 > N_EDGES) e1 = N_EDGES;
  int n = e1 - e0;
  for (int i = tid; i < NBUCK; i += 256) hist[i] = 0;
  __syncthreads();
  int2 ev[CBLK / 256];
  int nb[CBLK / 256];
#pragma unroll
  for (int j = 0; j < CBLK / 256; ++j) {
    int idx = e0 + j * 256 + tid;
    nb[j] = -1;
    if (idx < e1) {
      ev[j] = make_int2(src[idx], dst[idx]);
      nb[j] = ev[j].y >> BSHIFT;
      atomicAdd(&hist[nb[j]], 1);
    }
  }
  __syncthreads();
  int4 hv = *(const int4*)(hist + tid * 4);
  int s4 = hv.x + hv.y + hv.z + hv.w;
  int lane = tid & 63, wid = tid >> 6;
  int sc = s4;
#pragma unroll
  for (int off = 1; off < 64; off <<= 1) {
    int u = __shfl_up(sc, off, 64);
    if (lane >= off) sc += u;
  }
  if (lane == 63) wsum[wid] = sc;
  __syncthreads();
  int woff = 0;
#pragma unroll
  for (int w = 0; w < 4; ++w) woff += (w < wid) ? wsum[w] : 0;
  int excl = woff + sc - s4;
  loff[tid * 4 + 0] = excl;
  loff[tid * 4 + 1] = excl + hv.x;
  loff[tid * 4 + 2] = excl + hv.x + hv.y;
  loff[tid * 4 + 3] = excl + hv.x + hv.y + hv.z;
  __syncthreads();
  for (int b = tid; b < NBUCK; b += 256) {
    int c = hist[b];
    if (c > 0) gbase_s[b] = bucket_base[b] + atomicAdd(&bucket_fill[b], c);
    lcur[b] = loff[b];
  }
  __syncthreads();
#pragma unroll
  for (int j = 0; j < CBLK / 256; ++j) {
    if (nb[j] >= 0) {
      int p = atomicAdd(&lcur[nb[j]], 1);
      stage[p] = ev[j];
      sbuck[p] = (unsigned short)nb[j];
    }
  }
  __syncthreads();
  for (int s = tid; s < n; s += 256) {
    int b = sbuck[s];
    pairs[gbase_s[b] + (s - loff[b])] = stage[s];
  }
}

// ---------------- Pass D: per-bucket exact CSR (no global atomics) ----------------
__global__ __launch_bounds__(256) void k_bucket_csr(const int2* __restrict__ pairs, const int* __restrict__ base,
                                                    int* __restrict__ row_ptr, float* __restrict__ norm_dst,
                                                    int* __restrict__ csr_src) {
  __shared__ int hist[128];
  __shared__ int excl[129];
  __shared__ int curs[128];
  int bk = blockIdx.x;
  int b0 = base[bk], b1 = base[bk + 1];
  int tid = threadIdx.x;
  if (tid < 128) hist[tid] = 0;
  __syncthreads();
  for (int i = b0 + tid; i < b1; i += 256) atomicAdd(&hist[pairs[i].y & 127], 1);
  __syncthreads();
  if (tid < 128) {
    int v = hist[tid];
    int lane = tid & 63;
    int sc = v;
#pragma unroll
    for (int off = 1; off < 64; off <<= 1) {
      int u = __shfl_up(sc, off, 64);
      if (lane >= off) sc += u;
    }
    excl[tid] = sc - v;
    if (lane == 63 && tid < 64) excl[128] = sc;
  }
  __syncthreads();
  if (tid >= 64 && tid < 128) excl[tid] += excl[128];
  __syncthreads();
  int gbase = bk << BSHIFT;
  if (tid < 128) {
    int g = gbase + tid;
    if (g < N_NODES) {
      row_ptr[g] = b0 + excl[tid];
      norm_dst[g] = hist[tid] > 0 ? rsqrtf((float)hist[tid]) : 0.f;
    } else if (g == N_NODES) {
      row_ptr[N_NODES] = b0 + excl[tid];
    }
    curs[tid] = excl[tid];
  }
  __syncthreads();
  for (int i = b0 + tid; i < b1; i += 256) {
    int2 p = pairs[i];
    int pos = b0 + atomicAdd(&curs[p.y & 127], 1);
    csr_src[pos] = p.x;
  }
}

// ---------------- norm_src from deg_out ----------------
__global__ __launch_bounds__(256) void k_norms_src(const int* __restrict__ deg_out, float* __restrict__ norm_src) {
  int i = blockIdx.x * 256 + threadIdx.x;
  if (i < N_NODES) {
    int d = deg_out[i];
    norm_src[i] = d > 0 ? rsqrtf((float)d) : 0.f;
  }
}

// ---------------- embedding lookup: writes x (fp32) + xb (bf16, prescaled by norm_src) ----------------
__global__ __launch_bounds__(256) void k_embed(const int* __restrict__ h, const float* __restrict__ emb,
                                               const float* __restrict__ norm_src,
                                               float* __restrict__ x, unsigned short* __restrict__ xb) {
  int i = blockIdx.x * 256 + threadIdx.x;  // over N*32 float4
  const int total = N_NODES * (HID / 4);
  if (i < total) {
    int r = i >> 5, c = i & 31;
    float4 v = ((const float4*)emb)[h[r] * (HID / 4) + c];
    ((float4*)x)[i] = v;
    float ns = norm_src[r];
    uint2 p;
    p.x = (unsigned)f2bf(v.x * ns) | ((unsigned)f2bf(v.y * ns) << 16);
    p.y = (unsigned)f2bf(v.z * ns) | ((unsigned)f2bf(v.w * ns) << 16);
    *(uint2*)(xb + (size_t)i * 4) = p;
  }
}

// ---------------- W split+transpose: Wt[l][col][k] hi/lo bf16 ----------------
__global__ __launch_bounds__(128) void k_wsplit(const float* __restrict__ W, unsigned short* __restrict__ Wh,
                                                unsigned short* __restrict__ Wl) {
  int l = blockIdx.x >> 7, k = blockIdx.x & 127;
  int c = threadIdx.x;
  float w = W[(size_t)l * HID * HID + k * HID + c];
  unsigned short h = f2bf(w);
  Wh[(size_t)l * HID * HID + c * HID + k] = h;
  Wl[(size_t)l * HID * HID + c * HID + k] = f2bf(w - bf2f(h));
}

// ---------------- aggregation (prescaled bf16 gather, fp32 accumulate, hi/lo bf16 output) ----------------
__global__ __launch_bounds__(256) void k_agg(const unsigned short* __restrict__ xb, const int* __restrict__ row_ptr,
                                             const int* __restrict__ csr_src, const float* __restrict__ norm_dst,
                                             unsigned short* __restrict__ agg_hi, unsigned short* __restrict__ agg_lo) {
  int node = blockIdx.x * 16 + (threadIdx.x >> 4);
  int l16 = threadIdx.x & 15;
  if (node >= N_NODES) return;
  int s0 = row_ptr[node], s1 = row_ptr[node + 1];
  float acc[8];
#pragma unroll
  for (int j = 0; j < 8; ++j) acc[j] = 0.f;
  int i = s0;
  for (; i + 3 < s1; i += 4) {
    int sa = csr_src[i], sb = csr_src[i + 1], sc = csr_src[i + 2], sd = csr_src[i + 3];
    uint4 ua = *(const uint4*)(xb + (size_t)sa * HID + l16 * 8);
    uint4 ub = *(const uint4*)(xb + (size_t)sb * HID + l16 * 8);
    uint4 uc = *(const uint4*)(xb + (size_t)sc * HID + l16 * 8);
    uint4 ud = *(const uint4*)(xb + (size_t)sd * HID + l16 * 8);
    unsigned ue[4][4] = {{ua.x, ua.y, ua.z, ua.w}, {ub.x, ub.y, ub.z, ub.w},
                         {uc.x, uc.y, uc.z, uc.w}, {ud.x, ud.y, ud.z, ud.w}};
#pragma unroll
    for (int e = 0; e < 4; ++e)
#pragma unroll
      for (int q = 0; q < 4; ++q) {
        union { unsigned u; float f; } lo{ue[e][q] << 16}, hi{ue[e][q] & 0xffff0000u};
        acc[q * 2 + 0] += lo.f;
        acc[q * 2 + 1] += hi.f;
      }
  }
  for (; i < s1; ++i) {
    int s = csr_src[i];
    uint4 u = *(const uint4*)(xb + (size_t)s * HID + l16 * 8);
    unsigned uu[4] = {u.x, u.y, u.z, u.w};
#pragma unroll
    for (int q = 0; q < 4; ++q) {
      union { unsigned u; float f; } lo{uu[q] << 16}, hi{uu[q] & 0xffff0000u};
      acc[q * 2 + 0] += lo.f;
      acc[q * 2 + 1] += hi.f;
    }
  }
  float nd = norm_dst[node];
  unsigned short hh[8], ll[8];
#pragma unroll
  for (int j = 0; j < 8; ++j) {
    float v = acc[j] * nd;
    hh[j] = f2bf(v);
    ll[j] = f2bf(v - bf2f(hh[j]));
  }
  uint4 ho, lo4;
  ho.x = (unsigned)hh[0] | ((unsigned)hh[1] << 16); ho.y = (unsigned)hh[2] | ((unsigned)hh[3] << 16);
  ho.z = (unsigned)hh[4] | ((unsigned)hh[5] << 16); ho.w = (unsigned)hh[6] | ((unsigned)hh[7] << 16);
  lo4.x = (unsigned)ll[0] | ((unsigned)ll[1] << 16); lo4.y = (unsigned)ll[2] | ((unsigned)ll[3] << 16);
  lo4.z = (unsigned)ll[4] | ((unsigned)ll[5] << 16); lo4.w = (unsigned)ll[6] | ((unsigned)ll[7] << 16);
  *(uint4*)(agg_hi + (size_t)node * HID + l16 * 8) = ho;
  *(uint4*)(agg_lo + (size_t)node * HID + l16 * 8) = lo4;
}

// ---------------- MFMA GEMM: Y = A@W + b, bf16x3 (fp32-grade), fused BN stats ----------------
__global__ __launch_bounds__(256, 4) void k_gemm_mfma(const unsigned short* __restrict__ Ah,
                                                      const unsigned short* __restrict__ Al,
                                                      const unsigned short* __restrict__ Bh,
                                                      const unsigned short* __restrict__ Bl,
                                                      const float* __restrict__ bias, float* __restrict__ Y,
                                                      float* __restrict__ sums, float* __restrict__ sumsq) {
  __shared__ unsigned short sAh[128 * LSTR], sAl[128 * LSTR], sBh[128 * LSTR], sBl[128 * LSTR];  // 40960 B
  const int tid = threadIdx.x;
  const int lane = tid & 63, wid = tid >> 6;
  const int l15 = lane & 15, kg = lane >> 4;
  const int row0 = blockIdx.x * 128;

  f32x4 acc[2][8];
#pragma unroll
  for (int mi = 0; mi < 2; ++mi)
#pragma unroll
    for (int ni = 0; ni < 8; ++ni) acc[mi][ni] = (f32x4){0.f, 0.f, 0.f, 0.f};

  for (int kb = 0; kb < 4; ++kb) {
    const int k0 = kb * 32;
#pragma unroll
    for (int it = 0; it < 2; ++it) {
      int idx = tid * 2 + it;
      int r = idx >> 2, q = idx & 3;
      int gr = row0 + r;
      s16x8 vh = {0, 0, 0, 0, 0, 0, 0, 0}, vl = {0, 0, 0, 0, 0, 0, 0, 0};
      if (gr < N_NODES) {
        vh = *(const s16x8*)(Ah + (size_t)gr * HID + k0 + q * 8);
        vl = *(const s16x8*)(Al + (size_t)gr * HID + k0 + q * 8);
      }
      *(s16x8*)&sAh[r * LSTR + q * 8] = vh;
      *(s16x8*)&sAl[r * LSTR + q * 8] = vl;
      *(s16x8*)&sBh[r * LSTR + q * 8] = *(const s16x8*)(Bh + (size_t)r * HID + k0 + q * 8);
      *(s16x8*)&sBl[r * LSTR + q * 8] = *(const s16x8*)(Bl + (size_t)r * HID + k0 + q * 8);
    }
    __syncthreads();
    s16x8 afh[2], afl[2];
#pragma unroll
    for (int mi = 0; mi < 2; ++mi) {
      int ar = wid * 32 + mi * 16 + l15;
      afh[mi] = *(const s16x8*)&sAh[ar * LSTR + kg * 8];
      afl[mi] = *(const s16x8*)&sAl[ar * LSTR + kg * 8];
    }
#pragma unroll
    for (int ni = 0; ni < 8; ++ni) {
      int bc = ni * 16 + l15;
      s16x8 bh = *(const s16x8*)&sBh[bc * LSTR + kg * 8];
      s16x8 bl = *(const s16x8*)&sBl[bc * LSTR + kg * 8];
#pragma unroll
      for (int mi = 0; mi < 2; ++mi) {
        acc[mi][ni] = __builtin_amdgcn_mfma_f32_16x16x32_bf16(afh[mi], bh, acc[mi][ni], 0, 0, 0);
        acc[mi][ni] = __builtin_amdgcn_mfma_f32_16x16x32_bf16(afh[mi], bl, acc[mi][ni], 0, 0, 0);
        acc[mi][ni] = __builtin_amdgcn_mfma_f32_16x16x32_bf16(afl[mi], bh, acc[mi][ni], 0, 0, 0);
      }
    }
    __syncthreads();
  }

  float bv[8], sp[8], qp[8];
#pragma unroll
  for (int ni = 0; ni < 8; ++ni) {
    bv[ni] = bias[ni * 16 + l15];
    sp[ni] = 0.f; qp[ni] = 0.f;
  }
#pragma unroll
  for (int mi = 0; mi < 2; ++mi) {
    int rbase = row0 + wid * 32 + mi * 16 + kg * 4;
#pragma unroll
    for (int reg = 0; reg < 4; ++reg) {
      int r = rbase + reg;
      if (r < N_NODES) {
        float* yr = Y + (size_t)r * HID;
#pragma unroll
        for (int ni = 0; ni < 8; ++ni) {
          float y = acc[mi][ni][reg] + bv[ni];
          yr[ni * 16 + l15] = y;
          sp[ni] += y;
          qp[ni] += y * y;
        }
      }
    }
  }
  __syncthreads();
  float* red_s = (float*)sAh;  // [16][128] = 8KB
  float* red_q = (float*)sBh;
  int slot = wid * 4 + kg;
#pragma unroll
  for (int ni = 0; ni < 8; ++ni) {
    red_s[slot * 128 + ni * 16 + l15] = sp[ni];
    red_q[slot * 128 + ni * 16 + l15] = qp[ni];
  }
  __syncthreads();
  if (tid < 128) {
    float a = 0.f, b2 = 0.f;
#pragma unroll
    for (int s = 0; s < 16; ++s) {
      a += red_s[s * 128 + tid];
      b2 += red_q[s * 128 + tid];
    }
    atomicAdd(&sums[tid], a);
    atomicAdd(&sumsq[tid], b2);
  }
}

// ---------------- BN finalize ----------------
__global__ __launch_bounds__(128) void k_bn_final(const float* __restrict__ sums, const float* __restrict__ sumsq,
                                                  const float* __restrict__ gamma, const float* __restrict__ beta,
                                                  float* __restrict__ scale, float* __restrict__ shift) {
  int d = threadIdx.x;
  float mu = sums[d] / (float)N_NODES;
  float var = sumsq[d] / (float)N_NODES - mu * mu;
  float sc = gamma[d] * rsqrtf(var + EPSV);
  scale[d] = sc;
  shift[d] = beta[d] - mu * sc;
}

// ---------------- BN apply + relu + residual; writes x (fp32) + xb (bf16, prescaled) ----------------
__global__ __launch_bounds__(256) void k_bn_apply(const float* __restrict__ Y, const float* __restrict__ scale,
                                                  const float* __restrict__ shift, const float* __restrict__ norm_src,
                                                  float* __restrict__ x, unsigned short* __restrict__ xb) {
  int i = blockIdx.x * 256 + threadIdx.x;
  const int total = N_NODES * (HID / 4);
  if (i >= total) return;
  int c4 = i & 31, r = i >> 5;
  float4 y = ((const float4*)Y)[i];
  float4 sc = ((const float4*)scale)[c4];
  float4 sh = ((const float4*)shift)[c4];
  float4 xv = ((const float4*)x)[i];
  float4 o;
  o.x = fmaxf(y.x * sc.x + sh.x, 0.f) + xv.x;
  o.y = fmaxf(y.y * sc.y + sh.y, 0.f) + xv.y;
  o.z = fmaxf(y.z * sc.z + sh.z, 0.f) + xv.z;
  o.w = fmaxf(y.w * sc.w + sh.w, 0.f) + xv.w;
  ((float4*)x)[i] = o;
  float ns = norm_src[r];
  uint2 p;
  p.x = (unsigned)f2bf(o.x * ns) | ((unsigned)f2bf(o.y * ns) << 16);
  p.y = (unsigned)f2bf(o.z * ns) | ((unsigned)f2bf(o.w * ns) << 16);
  *(uint2*)(xb + (size_t)i * 4) = p;
}

// ---------------- fused layer-4 BN + MLP readout, 4-lane cooperative ----------------
// Group of 4 lanes handles 4 rows. Lane j owns h1 cols j*16..+15 (4 rows) -> 4x fewer LDS
// instructions per wave than 1-row/thread; h1/h2 exchanged via __shfl within the group.
__global__ __launch_bounds__(256) void k_mlp_bn_fused(const float* __restrict__ Yb, const float* __restrict__ Xres,
                                                      const float* __restrict__ scale, const float* __restrict__ shift,
                                                      const float* __restrict__ W1, const float* __restrict__ b1,
                                                      const float* __restrict__ W2, const float* __restrict__ b2,
                                                      const float* __restrict__ W3, const float* __restrict__ b3,
                                                      float* __restrict__ out) {
  __shared__ float Ws1[128 * 64];
  __shared__ float Ws2[64 * 32];
  __shared__ float Ws3[32 * 6];
  __shared__ float bs3[6];
  __shared__ float scs[128], shs[128];
  for (int i = threadIdx.x; i < 128 * 64; i += 256) Ws1[i] = W1[i];
  for (int i = threadIdx.x; i < 64 * 32; i += 256) Ws2[i] = W2[i];
  for (int i = threadIdx.x; i < 32 * 6; i += 256) Ws3[i] = W3[i];
  if (threadIdx.x < 6) bs3[threadIdx.x] = b3[threadIdx.x];
  if (threadIdx.x < 128) { scs[threadIdx.x] = scale[threadIdx.x]; shs[threadIdx.x] = shift[threadIdx.x]; }
  __syncthreads();
  const int j = threadIdx.x & 3;
  const int g = threadIdx.x >> 2;
  const int row0 = blockIdx.x * 256 + g * 4;
  const int lanebase = (threadIdx.x & 63) & ~3;

  bool vr[4];
#pragma unroll
  for (int r = 0; r < 4; ++r) vr[r] = (row0 + r) < N_NODES;

  float h1[4][16];
#pragma unroll
  for (int r = 0; r < 4; ++r)
#pragma unroll
    for (int t = 0; t < 16; ++t) h1[r][t] = b1[j * 16 + t];

  for (int k4 = 0; k4 < 32; ++k4) {
    float4 sc = *(const float4*)&scs[k4 * 4];
    float4 sh = *(const float4*)&shs[k4 * 4];
    float xs[4][4];
#pragma unroll
    for (int r = 0; r < 4; ++r) {
      if (vr[r]) {
        float4 yv = *(const float4*)(Yb + (size_t)(row0 + r) * 128 + k4 * 4);
        float4 xv = *(const float4*)(Xres + (size_t)(row0 + r) * 128 + k4 * 4);
        xs[r][0] = fmaxf(yv.x * sc.x + sh.x, 0.f) + xv.x;
        xs[r][1] = fmaxf(yv.y * sc.y + sh.y, 0.f) + xv.y;
        xs[r][2] = fmaxf(yv.z * sc.z + sh.z, 0.f) + xv.z;
        xs[r][3] = fmaxf(yv.w * sc.w + sh.w, 0.f) + xv.w;
      } else {
        xs[r][0] = xs[r][1] = xs[r][2] = xs[r][3] = 0.f;
      }
    }
#pragma unroll
    for (int kk = 0; kk < 4; ++kk) {
      int k = k4 * 4 + kk;
      float4 w0 = *(const float4*)&Ws1[k * 64 + j * 16];
      float4 w1 = *(const float4*)&Ws1[k * 64 + j * 16 + 4];
      float4 w2 = *(const float4*)&Ws1[k * 64 + j * 16 + 8];
      float4 w3 = *(const float4*)&Ws1[k * 64 + j * 16 + 12];
      float w[16] = {w0.x, w0.y, w0.z, w0.w, w1.x, w1.y, w1.z, w1.w,
                     w2.x, w2.y, w2.z, w2.w, w3.x, w3.y, w3.z, w3.w};
#pragma unroll
      for (int r = 0; r < 4; ++r)
#pragma unroll
        for (int t = 0; t < 16; ++t) h1[r][t] += xs[r][kk] * w[t];
    }
  }
  // relu in place
#pragma unroll
  for (int r = 0; r < 4; ++r)
#pragma unroll
    for (int t = 0; t < 16; ++t) h1[r][t] = fmaxf(h1[r][t], 0.f);

  float h2[4][8];
#pragma unroll
  for (int r = 0; r < 4; ++r)
#pragma unroll
    for (int o = 0; o < 8; ++o) h2[r][o] = b2[j * 8 + o];
#pragma unroll
  for (int c = 0; c < 64; ++c) {
    const int jp = c >> 4, t = c & 15;
    float4 w0 = *(const float4*)&Ws2[c * 32 + j * 8];
    float4 w1 = *(const float4*)&Ws2[c * 32 + j * 8 + 4];
#pragma unroll
    for (int r = 0; r < 4; ++r) {
      float hv = __shfl(h1[r][t], lanebase + jp, 64);
      h2[r][0] += hv * w0.x; h2[r][1] += hv * w0.y;
      h2[r][2] += hv * w0.z; h2[r][3] += hv * w0.w;
      h2[r][4] += hv * w1.x; h2[r][5] += hv * w1.y;
      h2[r][6] += hv * w1.z; h2[r][7] += hv * w1.w;
    }
  }

#pragma unroll
  for (int r = 0; r < 4; ++r) {
    float p[6] = {0.f, 0.f, 0.f, 0.f, 0.f, 0.f};
#pragma unroll
    for (int c2 = 0; c2 < 8; ++c2) {
      float hv = fmaxf(h2[r][c2], 0.f);
      const float* w3r = &Ws3[(j * 8 + c2) * 6];
#pragma unroll
      for (int o = 0; o < 6; ++o) p[o] += hv * w3r[o];
    }
#pragma unroll
    for (int o = 0; o < 6; ++o) {
      p[o] += __shfl_xor(p[o], 1, 64);
      p[o] += __shfl_xor(p[o], 2, 64);
    }
    if (j == 0 && vr[r]) {
      float* orow = out + (size_t)(row0 + r) * 6;
#pragma unroll
      for (int o = 0; o < 6; ++o) orow[o] = p[o] + bs3[o];
    }
  }
}

extern "C" void kernel_launch(void* const* d_in, const int* in_sizes, int n_in,
                              void* d_out, int out_size, void* d_ws, size_t ws_size,
                              hipStream_t stream) {
  const int* h = (const int*)d_in[0];
  const int* src = (const int*)d_in[1];
  const int* dst = (const int*)d_in[2];
  const float* emb = (const float*)d_in[3];
  const float* W = (const float*)d_in[4];
  const float* b = (const float*)d_in[5];
  const float* gamma = (const float*)d_in[6];
  const float* beta = (const float*)d_in[7];
  const float* W1 = (const float*)d_in[8];
  const float* b1 = (const float*)d_in[9];
  const float* W2 = (const float*)d_in[10];
  const float* b2 = (const float*)d_in[11];
  const float* W3 = (const float*)d_in[12];
  const float* b3 = (const float*)d_in[13];
  float* out = (float*)d_out;

  char* ws = (char*)d_ws;
  size_t off = 0;
  auto alloc = [&](size_t bytes) -> void* {
    void* p = ws + off;
    off += (bytes + 255) & ~(size_t)255;
    return p;
  };
  int* deg_out = (int*)alloc(N_NODES * 4);
  float* norm_src = (float*)alloc(N_NODES * 4);
  float* norm_dst = (float*)alloc(N_NODES * 4);
  int* row_ptr = (int*)alloc((N_NODES + 1) * 4);
  int* csr_src = (int*)alloc((size_t)N_EDGES * 4);
  int* bucket_cnt = (int*)alloc(NBUCK * 4);
  int* bucket_base = (int*)alloc((NBUCK + 1) * 4);
  int* bucket_fill = (int*)alloc(NBUCK * 4);
  float* x = (float*)alloc((size_t)N_NODES * HID * 4);
  unsigned short* xb = (unsigned short*)alloc((size_t)N_NODES * HID * 2);
  unsigned short* agg_hi = (unsigned short*)alloc((size_t)N_NODES * HID * 2);
  unsigned short* agg_lo = (unsigned short*)alloc((size_t)N_NODES * HID * 2);
  float* Yb = (float*)alloc((size_t)N_NODES * HID * 4);
  unsigned short* Wh = (unsigned short*)alloc((size_t)N_LAYERS * HID * HID * 2);
  unsigned short* Wl = (unsigned short*)alloc((size_t)N_LAYERS * HID * HID * 2);
  float* sums = (float*)alloc(512);
  float* sumsq = (float*)alloc(512);
  float* scale = (float*)alloc(512);
  float* shift = (float*)alloc(512);
  int2* pairs = (int2*)Yb;  // overlay: pairs (12.8MB) dead before Yb first written (layer-1 gemm)

  hipMemsetAsync(deg_out, 0, N_NODES * 4, stream);
  hipMemsetAsync(bucket_cnt, 0, NBUCK * 4, stream);
  k_hist<<<256, 256, 0, stream>>>(src, dst, bucket_cnt, deg_out);
  k_bscan<<<1, 256, 0, stream>>>(bucket_cnt, bucket_base, bucket_fill);
  k_scatter2<<<(N_EDGES + CBLK - 1) / CBLK, 256, 0, stream>>>(src, dst, bucket_base, bucket_fill, pairs);
  k_bucket_csr<<<NBUCK, 256, 0, stream>>>(pairs, bucket_base, row_ptr, norm_dst, csr_src);
  k_norms_src<<<(N_NODES + 255) / 256, 256, 0, stream>>>(deg_out, norm_src);
  k_embed<<<(N_NODES * (HID / 4) + 255) / 256, 256, 0, stream>>>(h, emb, norm_src, x, xb);
  k_wsplit<<<N_LAYERS * 128, 128, 0, stream>>>(W, Wh, Wl);

  for (int l = 0; l < N_LAYERS; ++l) {
    k_agg<<<(N_NODES + 15) / 16, 256, 0, stream>>>(xb, row_ptr, csr_src, norm_dst, agg_hi, agg_lo);
    hipMemsetAsync(sums, 0, 1024, stream);  // sums+sumsq contiguous
    k_gemm_mfma<<<(N_NODES + 127) / 128, 256, 0, stream>>>(agg_hi, agg_lo,
                                                           Wh + (size_t)l * HID * HID, Wl + (size_t)l * HID * HID,
                                                           b + l * HID, Yb, sums, sumsq);
    k_bn_final<<<1, 128, 0, stream>>>(sums, sumsq, gamma + l * HID, beta + l * HID, scale, shift);
    if (l < N_LAYERS - 1) {
      k_bn_apply<<<(N_NODES * (HID / 4) + 255) / 256, 256, 0, stream>>>(Yb, scale, shift, norm_src, x, xb);
    }
  }
  k_mlp_bn_fused<<<(N_NODES + 255) / 256, 256, 0, stream>>>(Yb, x, scale, shift,
                                                            W1, b1, W2, b2, W3, b3, out);
}

// Round 11
// 678.999 us; speedup vs baseline: 1.3697x; 1.3697x over previous
//
#include <hip/hip_runtime.h>

#define N_NODES 100000
#define N_EDGES 1600000
#define HID 128
#define N_LAYERS 4
#define EPSV 1e-5f
#define NBUCK 1024
#define BSHIFT 7      // 128 nodes per bucket
#define CBLK 4096     // edges per scatter block
#define LSTR 40       // LDS row stride in shorts (80B: 16B-aligned, 2-way-max bank conflicts = free)

using f32x4 = __attribute__((ext_vector_type(4))) float;
using s16x8 = __attribute__((ext_vector_type(8))) short;

__device__ __forceinline__ unsigned short f2bf(float f) {
  union { float f; unsigned u; } c{f};
  unsigned u = c.u;
  return (unsigned short)((u + 0x7fffu + ((u >> 16) & 1u)) >> 16);
}
__device__ __forceinline__ float bf2f(unsigned short s) {
  union { unsigned u; float f; } c{(unsigned)s << 16};
  return c.f;
}

// ---------------- Pass A: bucket histogram (LDS) + deg_out atomics ----------------
__global__ __launch_bounds__(256) void k_hist(const int* __restrict__ src, const int* __restrict__ dst,
                                              int* __restrict__ bucket_cnt, int* __restrict__ deg_out) {
  __shared__ int h[NBUCK];
  for (int i = threadIdx.x; i < NBUCK; i += 256) h[i] = 0;
  __syncthreads();
  int per = (N_EDGES + gridDim.x - 1) / gridDim.x;
  int lo = blockIdx.x * per;
  int hi = lo + per; if (hi > N_EDGES) hi = N_EDGES;
  for (int i = lo + threadIdx.x; i < hi; i += 256) {
    atomicAdd(&h[dst[i] >> BSHIFT], 1);
    atomicAdd(&deg_out[src[i]], 1);
  }
  __syncthreads();
  for (int i = threadIdx.x; i < NBUCK; i += 256)
    if (h[i]) atomicAdd(&bucket_cnt[i], h[i]);
}

// ---------------- Pass B: scan 1024 bucket counts; zero bucket_fill ----------------
__global__ __launch_bounds__(256) void k_bscan(const int* __restrict__ cnt, int* __restrict__ base,
                                               int* __restrict__ fill) {
  __shared__ int wsum[4];
  int tid = threadIdx.x;
  int4 v = *(const int4*)(cnt + tid * 4);
  int s4 = v.x + v.y + v.z + v.w;
  int lane = tid & 63, wid = tid >> 6;
  int sc = s4;
#pragma unroll
  for (int off = 1; off < 64; off <<= 1) {
    int u = __shfl_up(sc, off, 64);
    if (lane >= off) sc += u;
  }
  if (lane == 63) wsum[wid] = sc;
  __syncthreads();
  int woff = 0;
#pragma unroll
  for (int w = 0; w < 4; ++w) woff += (w < wid) ? wsum[w] : 0;
  int excl = woff + sc - s4;
  int4 o;
  o.x = excl; o.y = o.x + v.x; o.z = o.y + v.y; o.w = o.z + v.z;
  *(int4*)(base + tid * 4) = o;
  *(int4*)(fill + tid * 4) = make_int4(0, 0, 0, 0);
  if (tid == 255) base[NBUCK] = woff + sc;  // == N_EDGES
}

// ---------------- Pass C: block-local staged scatter (coalesced, no serialization) ----------------
__global__ __launch_bounds__(256) void k_scatter2(const int* __restrict__ src, const int* __restrict__ dst,
                                                  const int* __restrict__ bucket_base, int* __restrict__ bucket_fill,
                                                  int2* __restrict__ pairs) {
  __shared__ int hist[NBUCK];
  __shared__ int loff[NBUCK];
  __shared__ int gbase_s[NBUCK];
  __shared__ int lcur[NBUCK];
  __shared__ int wsum[4];
  __shared__ int2 stage[CBLK];                 // 32 KB
  __shared__ unsigned short sbuck[CBLK];       // 8 KB
  int tid = threadIdx.x;
  int e0 = blockIdx.x * CBLK;
  int e1 = e0 + CBLK; if (e1 > N_EDGES) e1 = N_EDGES;
  int n = e1 - e0;
  for (int i = tid; i < NBUCK; i += 256) hist[i] = 0;
  __syncthreads();
  int2 ev[CBLK / 256];
  int nb[CBLK / 256];
#pragma unroll
  for (int j = 0; j < CBLK / 256; ++j) {
    int idx = e0 + j * 256 + tid;
    nb[j] = -1;
    if (idx < e1) {
      ev[j] = make_int2(src[idx], dst[idx]);
      nb[j] = ev[j].y >> BSHIFT;
      atomicAdd(&hist[nb[j]], 1);
    }
  }
  __syncthreads();
  int4 hv = *(const int4*)(hist + tid * 4);
  int s4 = hv.x + hv.y + hv.z + hv.w;
  int lane = tid & 63, wid = tid >> 6;
  int sc = s4;
#pragma unroll
  for (int off = 1; off < 64; off <<= 1) {
    int u = __shfl_up(sc, off, 64);
    if (lane >= off) sc += u;
  }
  if (lane == 63) wsum[wid] = sc;
  __syncthreads();
  int woff = 0;
#pragma unroll
  for (int w = 0; w < 4; ++w) woff += (w < wid) ? wsum[w] : 0;
  int excl = woff + sc - s4;
  loff[tid * 4 + 0] = excl;
  loff[tid * 4 + 1] = excl + hv.x;
  loff[tid * 4 + 2] = excl + hv.x + hv.y;
  loff[tid * 4 + 3] = excl + hv.x + hv.y + hv.z;
  __syncthreads();
  for (int b = tid; b < NBUCK; b += 256) {
    int c = hist[b];
    if (c > 0) gbase_s[b] = bucket_base[b] + atomicAdd(&bucket_fill[b], c);
    lcur[b] = loff[b];
  }
  __syncthreads();
#pragma unroll
  for (int j = 0; j < CBLK / 256; ++j) {
    if (nb[j] >= 0) {
      int p = atomicAdd(&lcur[nb[j]], 1);
      stage[p] = ev[j];
      sbuck[p] = (unsigned short)nb[j];
    }
  }
  __syncthreads();
  for (int s = tid; s < n; s += 256) {
    int b = sbuck[s];
    pairs[gbase_s[b] + (s - loff[b])] = stage[s];
  }
}

// ---------------- Pass D: per-bucket exact CSR (no global atomics) ----------------
__global__ __launch_bounds__(256) void k_bucket_csr(const int2* __restrict__ pairs, const int* __restrict__ base,
                                                    int* __restrict__ row_ptr, float* __restrict__ norm_dst,
                                                    int* __restrict__ csr_src) {
  __shared__ int hist[128];
  __shared__ int excl[129];
  __shared__ int curs[128];
  int bk = blockIdx.x;
  int b0 = base[bk], b1 = base[bk + 1];
  int tid = threadIdx.x;
  if (tid < 128) hist[tid] = 0;
  __syncthreads();
  for (int i = b0 + tid; i < b1; i += 256) atomicAdd(&hist[pairs[i].y & 127], 1);
  __syncthreads();
  if (tid < 128) {
    int v = hist[tid];
    int lane = tid & 63;
    int sc = v;
#pragma unroll
    for (int off = 1; off < 64; off <<= 1) {
      int u = __shfl_up(sc, off, 64);
      if (lane >= off) sc += u;
    }
    excl[tid] = sc - v;
    if (lane == 63 && tid < 64) excl[128] = sc;
  }
  __syncthreads();
  if (tid >= 64 && tid < 128) excl[tid] += excl[128];
  __syncthreads();
  int gbase = bk << BSHIFT;
  if (tid < 128) {
    int g = gbase + tid;
    if (g < N_NODES) {
      row_ptr[g] = b0 + excl[tid];
      norm_dst[g] = hist[tid] > 0 ? rsqrtf((float)hist[tid]) : 0.f;
    } else if (g == N_NODES) {
      row_ptr[N_NODES] = b0 + excl[tid];
    }
    curs[tid] = excl[tid];
  }
  __syncthreads();
  for (int i = b0 + tid; i < b1; i += 256) {
    int2 p = pairs[i];
    int pos = b0 + atomicAdd(&curs[p.y & 127], 1);
    csr_src[pos] = p.x;
  }
}

// ---------------- norm_src from deg_out ----------------
__global__ __launch_bounds__(256) void k_norms_src(const int* __restrict__ deg_out, float* __restrict__ norm_src) {
  int i = blockIdx.x * 256 + threadIdx.x;
  if (i < N_NODES) {
    int d = deg_out[i];
    norm_src[i] = d > 0 ? rsqrtf((float)d) : 0.f;
  }
}

// ---------------- embedding lookup: writes x (fp32) + xb (bf16, prescaled by norm_src) ----------------
__global__ __launch_bounds__(256) void k_embed(const int* __restrict__ h, const float* __restrict__ emb,
                                               const float* __restrict__ norm_src,
                                               float* __restrict__ x, unsigned short* __restrict__ xb) {
  int i = blockIdx.x * 256 + threadIdx.x;  // over N*32 float4
  const int total = N_NODES * (HID / 4);
  if (i < total) {
    int r = i >> 5, c = i & 31;
    float4 v = ((const float4*)emb)[h[r] * (HID / 4) + c];
    ((float4*)x)[i] = v;
    float ns = norm_src[r];
    uint2 p;
    p.x = (unsigned)f2bf(v.x * ns) | ((unsigned)f2bf(v.y * ns) << 16);
    p.y = (unsigned)f2bf(v.z * ns) | ((unsigned)f2bf(v.w * ns) << 16);
    *(uint2*)(xb + (size_t)i * 4) = p;
  }
}

// ---------------- W split+transpose: Wt[l][col][k] hi/lo bf16 (GCN layers) ----------------
__global__ __launch_bounds__(128) void k_wsplit(const float* __restrict__ W, unsigned short* __restrict__ Wh,
                                                unsigned short* __restrict__ Wl) {
  int l = blockIdx.x >> 7, k = blockIdx.x & 127;
  int c = threadIdx.x;
  float w = W[(size_t)l * HID * HID + k * HID + c];
  unsigned short h = f2bf(w);
  Wh[(size_t)l * HID * HID + c * HID + k] = h;
  Wl[(size_t)l * HID * HID + c * HID + k] = f2bf(w - bf2f(h));
}

// ---------------- generic W split+transpose for MLP weights: [K][C] -> hi/lo [C][K] ----------------
__global__ __launch_bounds__(256) void k_wsplit_t(const float* __restrict__ Win,
                                                  unsigned short* __restrict__ Wth,
                                                  unsigned short* __restrict__ Wtl, int K, int C) {
  int idx = blockIdx.x * 256 + threadIdx.x;
  if (idx < K * C) {
    int k = idx / C, c = idx - k * C;
    float w = Win[idx];
    unsigned short h = f2bf(w);
    Wth[(size_t)c * K + k] = h;
    Wtl[(size_t)c * K + k] = f2bf(w - bf2f(h));
  }
}

// ---------------- aggregation (prescaled bf16 gather, fp32 accumulate, hi/lo bf16 output) ----------------
__global__ __launch_bounds__(256) void k_agg(const unsigned short* __restrict__ xb, const int* __restrict__ row_ptr,
                                             const int* __restrict__ csr_src, const float* __restrict__ norm_dst,
                                             unsigned short* __restrict__ agg_hi, unsigned short* __restrict__ agg_lo) {
  int node = blockIdx.x * 16 + (threadIdx.x >> 4);
  int l16 = threadIdx.x & 15;
  if (node >= N_NODES) return;
  int s0 = row_ptr[node], s1 = row_ptr[node + 1];
  float acc[8];
#pragma unroll
  for (int j = 0; j < 8; ++j) acc[j] = 0.f;
  int i = s0;
  for (; i + 3 < s1; i += 4) {
    int sa = csr_src[i], sb = csr_src[i + 1], sc = csr_src[i + 2], sd = csr_src[i + 3];
    uint4 ua = *(const uint4*)(xb + (size_t)sa * HID + l16 * 8);
    uint4 ub = *(const uint4*)(xb + (size_t)sb * HID + l16 * 8);
    uint4 uc = *(const uint4*)(xb + (size_t)sc * HID + l16 * 8);
    uint4 ud = *(const uint4*)(xb + (size_t)sd * HID + l16 * 8);
    unsigned ue[4][4] = {{ua.x, ua.y, ua.z, ua.w}, {ub.x, ub.y, ub.z, ub.w},
                         {uc.x, uc.y, uc.z, uc.w}, {ud.x, ud.y, ud.z, ud.w}};
#pragma unroll
    for (int e = 0; e < 4; ++e)
#pragma unroll
      for (int q = 0; q < 4; ++q) {
        union { unsigned u; float f; } lo{ue[e][q] << 16}, hi{ue[e][q] & 0xffff0000u};
        acc[q * 2 + 0] += lo.f;
        acc[q * 2 + 1] += hi.f;
      }
  }
  for (; i < s1; ++i) {
    int s = csr_src[i];
    uint4 u = *(const uint4*)(xb + (size_t)s * HID + l16 * 8);
    unsigned uu[4] = {u.x, u.y, u.z, u.w};
#pragma unroll
    for (int q = 0; q < 4; ++q) {
      union { unsigned u; float f; } lo{uu[q] << 16}, hi{uu[q] & 0xffff0000u};
      acc[q * 2 + 0] += lo.f;
      acc[q * 2 + 1] += hi.f;
    }
  }
  float nd = norm_dst[node];
  unsigned short hh[8], ll[8];
#pragma unroll
  for (int j = 0; j < 8; ++j) {
    float v = acc[j] * nd;
    hh[j] = f2bf(v);
    ll[j] = f2bf(v - bf2f(hh[j]));
  }
  uint4 ho, lo4;
  ho.x = (unsigned)hh[0] | ((unsigned)hh[1] << 16); ho.y = (unsigned)hh[2] | ((unsigned)hh[3] << 16);
  ho.z = (unsigned)hh[4] | ((unsigned)hh[5] << 16); ho.w = (unsigned)hh[6] | ((unsigned)hh[7] << 16);
  lo4.x = (unsigned)ll[0] | ((unsigned)ll[1] << 16); lo4.y = (unsigned)ll[2] | ((unsigned)ll[3] << 16);
  lo4.z = (unsigned)ll[4] | ((unsigned)ll[5] << 16); lo4.w = (unsigned)ll[6] | ((unsigned)ll[7] << 16);
  *(uint4*)(agg_hi + (size_t)node * HID + l16 * 8) = ho;
  *(uint4*)(agg_lo + (size_t)node * HID + l16 * 8) = lo4;
}

// ---------------- MFMA GEMM: Y = A@W + b, bf16x3 (fp32-grade), fused BN stats ----------------
__global__ __launch_bounds__(256, 4) void k_gemm_mfma(const unsigned short* __restrict__ Ah,
                                                      const unsigned short* __restrict__ Al,
                                                      const unsigned short* __restrict__ Bh,
                                                      const unsigned short* __restrict__ Bl,
                                                      const float* __restrict__ bias, float* __restrict__ Y,
                                                      float* __restrict__ sums, float* __restrict__ sumsq) {
  __shared__ unsigned short sAh[128 * LSTR], sAl[128 * LSTR], sBh[128 * LSTR], sBl[128 * LSTR];  // 40960 B
  const int tid = threadIdx.x;
  const int lane = tid & 63, wid = tid >> 6;
  const int l15 = lane & 15, kg = lane >> 4;
  const int row0 = blockIdx.x * 128;

  f32x4 acc[2][8];
#pragma unroll
  for (int mi = 0; mi < 2; ++mi)
#pragma unroll
    for (int ni = 0; ni < 8; ++ni) acc[mi][ni] = (f32x4){0.f, 0.f, 0.f, 0.f};

  for (int kb = 0; kb < 4; ++kb) {
    const int k0 = kb * 32;
#pragma unroll
    for (int it = 0; it < 2; ++it) {
      int idx = tid * 2 + it;
      int r = idx >> 2, q = idx & 3;
      int gr = row0 + r;
      s16x8 vh = {0, 0, 0, 0, 0, 0, 0, 0}, vl = {0, 0, 0, 0, 0, 0, 0, 0};
      if (gr < N_NODES) {
        vh = *(const s16x8*)(Ah + (size_t)gr * HID + k0 + q * 8);
        vl = *(const s16x8*)(Al + (size_t)gr * HID + k0 + q * 8);
      }
      *(s16x8*)&sAh[r * LSTR + q * 8] = vh;
      *(s16x8*)&sAl[r * LSTR + q * 8] = vl;
      *(s16x8*)&sBh[r * LSTR + q * 8] = *(const s16x8*)(Bh + (size_t)r * HID + k0 + q * 8);
      *(s16x8*)&sBl[r * LSTR + q * 8] = *(const s16x8*)(Bl + (size_t)r * HID + k0 + q * 8);
    }
    __syncthreads();
    s16x8 afh[2], afl[2];
#pragma unroll
    for (int mi = 0; mi < 2; ++mi) {
      int ar = wid * 32 + mi * 16 + l15;
      afh[mi] = *(const s16x8*)&sAh[ar * LSTR + kg * 8];
      afl[mi] = *(const s16x8*)&sAl[ar * LSTR + kg * 8];
    }
#pragma unroll
    for (int ni = 0; ni < 8; ++ni) {
      int bc = ni * 16 + l15;
      s16x8 bh = *(const s16x8*)&sBh[bc * LSTR + kg * 8];
      s16x8 bl = *(const s16x8*)&sBl[bc * LSTR + kg * 8];
#pragma unroll
      for (int mi = 0; mi < 2; ++mi) {
        acc[mi][ni] = __builtin_amdgcn_mfma_f32_16x16x32_bf16(afh[mi], bh, acc[mi][ni], 0, 0, 0);
        acc[mi][ni] = __builtin_amdgcn_mfma_f32_16x16x32_bf16(afh[mi], bl, acc[mi][ni], 0, 0, 0);
        acc[mi][ni] = __builtin_amdgcn_mfma_f32_16x16x32_bf16(afl[mi], bh, acc[mi][ni], 0, 0, 0);
      }
    }
    __syncthreads();
  }

  float bv[8], sp[8], qp[8];
#pragma unroll
  for (int ni = 0; ni < 8; ++ni) {
    bv[ni] = bias[ni * 16 + l15];
    sp[ni] = 0.f; qp[ni] = 0.f;
  }
#pragma unroll
  for (int mi = 0; mi < 2; ++mi) {
    int rbase = row0 + wid * 32 + mi * 16 + kg * 4;
#pragma unroll
    for (int reg = 0; reg < 4; ++reg) {
      int r = rbase + reg;
      if (r < N_NODES) {
        float* yr = Y + (size_t)r * HID;
#pragma unroll
        for (int ni = 0; ni < 8; ++ni) {
          float y = acc[mi][ni][reg] + bv[ni];
          yr[ni * 16 + l15] = y;
          sp[ni] += y;
          qp[ni] += y * y;
        }
      }
    }
  }
  __syncthreads();
  float* red_s = (float*)sAh;  // [16][128] = 8KB
  float* red_q = (float*)sBh;
  int slot = wid * 4 + kg;
#pragma unroll
  for (int ni = 0; ni < 8; ++ni) {
    red_s[slot * 128 + ni * 16 + l15] = sp[ni];
    red_q[slot * 128 + ni * 16 + l15] = qp[ni];
  }
  __syncthreads();
  if (tid < 128) {
    float a = 0.f, b2 = 0.f;
#pragma unroll
    for (int s = 0; s < 16; ++s) {
      a += red_s[s * 128 + tid];
      b2 += red_q[s * 128 + tid];
    }
    atomicAdd(&sums[tid], a);
    atomicAdd(&sumsq[tid], b2);
  }
}

// ---------------- BN finalize ----------------
__global__ __launch_bounds__(128) void k_bn_final(const float* __restrict__ sums, const float* __restrict__ sumsq,
                                                  const float* __restrict__ gamma, const float* __restrict__ beta,
                                                  float* __restrict__ scale, float* __restrict__ shift) {
  int d = threadIdx.x;
  float mu = sums[d] / (float)N_NODES;
  float var = sumsq[d] / (float)N_NODES - mu * mu;
  float sc = gamma[d] * rsqrtf(var + EPSV);
  scale[d] = sc;
  shift[d] = beta[d] - mu * sc;
}

// ---------------- BN apply + relu + residual; writes x (fp32) + xb (bf16, prescaled) ----------------
__global__ __launch_bounds__(256) void k_bn_apply(const float* __restrict__ Y, const float* __restrict__ scale,
                                                  const float* __restrict__ shift, const float* __restrict__ norm_src,
                                                  float* __restrict__ x, unsigned short* __restrict__ xb) {
  int i = blockIdx.x * 256 + threadIdx.x;
  const int total = N_NODES * (HID / 4);
  if (i >= total) return;
  int c4 = i & 31, r = i >> 5;
  float4 y = ((const float4*)Y)[i];
  float4 sc = ((const float4*)scale)[c4];
  float4 sh = ((const float4*)shift)[c4];
  float4 xv = ((const float4*)x)[i];
  float4 o;
  o.x = fmaxf(y.x * sc.x + sh.x, 0.f) + xv.x;
  o.y = fmaxf(y.y * sc.y + sh.y, 0.f) + xv.y;
  o.z = fmaxf(y.z * sc.z + sh.z, 0.f) + xv.z;
  o.w = fmaxf(y.w * sc.w + sh.w, 0.f) + xv.w;
  ((float4*)x)[i] = o;
  float ns = norm_src[r];
  uint2 p;
  p.x = (unsigned)f2bf(o.x * ns) | ((unsigned)f2bf(o.y * ns) << 16);
  p.y = (unsigned)f2bf(o.z * ns) | ((unsigned)f2bf(o.w * ns) << 16);
  *(uint2*)(xb + (size_t)i * 4) = p;
}

// ---------------- MFMA readout: BN(l=3) + residual -> 128->64->32->6 ----------------
// Layer 1+2 via MFMA bf16x3 (weight fragments in registers, zero LDS weight re-reads);
// h1 round-trips LDS as hi/lo bf16 (C-layout write -> A-layout read); layer 3 per-thread.
__global__ __launch_bounds__(256, 4) void k_readout(const float* __restrict__ Yb, const float* __restrict__ Xres,
                                                    const float* __restrict__ scale, const float* __restrict__ shift,
                                                    const unsigned short* __restrict__ B1h, const unsigned short* __restrict__ B1l,
                                                    const float* __restrict__ b1,
                                                    const unsigned short* __restrict__ B2h, const unsigned short* __restrict__ B2l,
                                                    const float* __restrict__ b2,
                                                    const float* __restrict__ W3, const float* __restrict__ b3,
                                                    float* __restrict__ out) {
  __shared__ unsigned short sAh[128 * 72], sAl[128 * 72];  // 36864 B (slabs, then h1, then h2-as-float)
  __shared__ float scs[128], shs[128];
  __shared__ float Ws3s[192];
  const int tid = threadIdx.x;
  const int lane = tid & 63, wid = tid >> 6;
  const int l15 = lane & 15, kg = lane >> 4;
  const int row0 = blockIdx.x * 128;
  if (tid < 128) { scs[tid] = scale[tid]; shs[tid] = shift[tid]; }
  if (tid < 192) Ws3s[tid] = W3[tid];
  __syncthreads();

  f32x4 acc1[2][4];
#pragma unroll
  for (int mi = 0; mi < 2; ++mi)
#pragma unroll
    for (int ni = 0; ni < 4; ++ni) acc1[mi][ni] = (f32x4){0.f, 0.f, 0.f, 0.f};

  // ---- layer 1: two K-slabs of 64 ----
  for (int slab = 0; slab < 2; ++slab) {
    const int c0 = slab * 64;
    // stage x4 = relu(Yb*sc+sh)+Xres as hi/lo bf16, rows 0..127 x cols c0..c0+63
#pragma unroll
    for (int it = 0; it < 4; ++it) {
      int idx = tid + it * 256;        // 0..1023
      int r = idx >> 3, q = idx & 7;   // row, 8-col chunk
      int gr = row0 + r;
      float v[8];
      if (gr < N_NODES) {
        const float* yp = Yb + (size_t)gr * HID + c0 + q * 8;
        const float* xp = Xres + (size_t)gr * HID + c0 + q * 8;
        float4 y0 = *(const float4*)yp, y1 = *(const float4*)(yp + 4);
        float4 x0 = *(const float4*)xp, x1 = *(const float4*)(xp + 4);
        const float* scp = &scs[c0 + q * 8];
        const float* shp = &shs[c0 + q * 8];
        v[0] = fmaxf(y0.x * scp[0] + shp[0], 0.f) + x0.x;
        v[1] = fmaxf(y0.y * scp[1] + shp[1], 0.f) + x0.y;
        v[2] = fmaxf(y0.z * scp[2] + shp[2], 0.f) + x0.z;
        v[3] = fmaxf(y0.w * scp[3] + shp[3], 0.f) + x0.w;
        v[4] = fmaxf(y1.x * scp[4] + shp[4], 0.f) + x1.x;
        v[5] = fmaxf(y1.y * scp[5] + shp[5], 0.f) + x1.y;
        v[6] = fmaxf(y1.z * scp[6] + shp[6], 0.f) + x1.z;
        v[7] = fmaxf(y1.w * scp[7] + shp[7], 0.f) + x1.w;
      } else {
#pragma unroll
        for (int j = 0; j < 8; ++j) v[j] = 0.f;
      }
      short hh[8], ll[8];
#pragma unroll
      for (int j = 0; j < 8; ++j) {
        unsigned short hb = f2bf(v[j]);
        hh[j] = (short)hb;
        ll[j] = (short)f2bf(v[j] - bf2f(hb));
      }
      *(s16x8*)&sAh[r * 72 + q * 8] = (s16x8){hh[0], hh[1], hh[2], hh[3], hh[4], hh[5], hh[6], hh[7]};
      *(s16x8*)&sAl[r * 72 + q * 8] = (s16x8){ll[0], ll[1], ll[2], ll[3], ll[4], ll[5], ll[6], ll[7]};
    }
    __syncthreads();
#pragma unroll
    for (int kb = 0; kb < 2; ++kb) {
      s16x8 afh[2], afl[2];
#pragma unroll
      for (int mi = 0; mi < 2; ++mi) {
        int ar = wid * 32 + mi * 16 + l15;
        afh[mi] = *(const s16x8*)&sAh[ar * 72 + kb * 32 + kg * 8];
        afl[mi] = *(const s16x8*)&sAl[ar * 72 + kb * 32 + kg * 8];
      }
#pragma unroll
      for (int ni = 0; ni < 4; ++ni) {
        int bc = ni * 16 + l15;
        s16x8 bh = *(const s16x8*)(B1h + (size_t)bc * 128 + c0 + kb * 32 + kg * 8);
        s16x8 bl = *(const s16x8*)(B1l + (size_t)bc * 128 + c0 + kb * 32 + kg * 8);
#pragma unroll
        for (int mi = 0; mi < 2; ++mi) {
          acc1[mi][ni] = __builtin_amdgcn_mfma_f32_16x16x32_bf16(afh[mi], bh, acc1[mi][ni], 0, 0, 0);
          acc1[mi][ni] = __builtin_amdgcn_mfma_f32_16x16x32_bf16(afh[mi], bl, acc1[mi][ni], 0, 0, 0);
          acc1[mi][ni] = __builtin_amdgcn_mfma_f32_16x16x32_bf16(afl[mi], bh, acc1[mi][ni], 0, 0, 0);
        }
      }
    }
    __syncthreads();
  }

  // ---- h1 = relu(acc1 + b1) -> LDS hi/lo (C layout: row=kg*4+reg, col=ni*16+l15) ----
  float bv1[4];
#pragma unroll
  for (int ni = 0; ni < 4; ++ni) bv1[ni] = b1[ni * 16 + l15];
#pragma unroll
  for (int mi = 0; mi < 2; ++mi)
#pragma unroll
    for (int ni = 0; ni < 4; ++ni)
#pragma unroll
      for (int reg = 0; reg < 4; ++reg) {
        int rr = wid * 32 + mi * 16 + kg * 4 + reg;
        float v = fmaxf(acc1[mi][ni][reg] + bv1[ni], 0.f);
        unsigned short hb = f2bf(v);
        sAh[rr * 72 + ni * 16 + l15] = hb;
        sAl[rr * 72 + ni * 16 + l15] = f2bf(v - bf2f(hb));
      }
  __syncthreads();

  // ---- layer 2: h2 = relu(h1) @ W2 + b2 via MFMA, K=64 ----
  f32x4 acc2[2][2];
#pragma unroll
  for (int mi = 0; mi < 2; ++mi)
#pragma unroll
    for (int ni = 0; ni < 2; ++ni) acc2[mi][ni] = (f32x4){0.f, 0.f, 0.f, 0.f};
#pragma unroll
  for (int kb = 0; kb < 2; ++kb) {
    s16x8 afh[2], afl[2];
#pragma unroll
    for (int mi = 0; mi < 2; ++mi) {
      int ar = wid * 32 + mi * 16 + l15;
      afh[mi] = *(const s16x8*)&sAh[ar * 72 + kb * 32 + kg * 8];
      afl[mi] = *(const s16x8*)&sAl[ar * 72 + kb * 32 + kg * 8];
    }
#pragma unroll
    for (int ni = 0; ni < 2; ++ni) {
      int bc = ni * 16 + l15;
      s16x8 bh = *(const s16x8*)(B2h + (size_t)bc * 64 + kb * 32 + kg * 8);
      s16x8 bl = *(const s16x8*)(B2l + (size_t)bc * 64 + kb * 32 + kg * 8);
#pragma unroll
      for (int mi = 0; mi < 2; ++mi) {
        acc2[mi][ni] = __builtin_amdgcn_mfma_f32_16x16x32_bf16(afh[mi], bh, acc2[mi][ni], 0, 0, 0);
        acc2[mi][ni] = __builtin_amdgcn_mfma_f32_16x16x32_bf16(afh[mi], bl, acc2[mi][ni], 0, 0, 0);
        acc2[mi][ni] = __builtin_amdgcn_mfma_f32_16x16x32_bf16(afl[mi], bh, acc2[mi][ni], 0, 0, 0);
      }
    }
  }
  __syncthreads();

  // ---- h2 = relu(acc2 + b2) -> LDS fp32 [128][36] ----
  float* h2s = (float*)sAh;
  float bv2[2];
#pragma unroll
  for (int ni = 0; ni < 2; ++ni) bv2[ni] = b2[ni * 16 + l15];
#pragma unroll
  for (int mi = 0; mi < 2; ++mi)
#pragma unroll
    for (int ni = 0; ni < 2; ++ni)
#pragma unroll
      for (int reg = 0; reg < 4; ++reg) {
        int rr = wid * 32 + mi * 16 + kg * 4 + reg;
        h2s[rr * 36 + ni * 16 + l15] = fmaxf(acc2[mi][ni][reg] + bv2[ni], 0.f);
      }
  __syncthreads();

  // ---- layer 3: per-thread (tid<128 -> one row), Ws3 broadcast reads ----
  if (tid < 128) {
    int gr = row0 + tid;
    if (gr < N_NODES) {
      float h2r[32];
#pragma unroll
      for (int q = 0; q < 8; ++q) {
        float4 t = *(const float4*)&h2s[tid * 36 + q * 4];
        h2r[q * 4 + 0] = t.x; h2r[q * 4 + 1] = t.y; h2r[q * 4 + 2] = t.z; h2r[q * 4 + 3] = t.w;
      }
      float p[6];
#pragma unroll
      for (int o = 0; o < 6; ++o) p[o] = b3[o];
#pragma unroll
      for (int k = 0; k < 32; ++k)
#pragma unroll
        for (int o = 0; o < 6; ++o) p[o] += h2r[k] * Ws3s[k * 6 + o];
      float* orow = out + (size_t)gr * 6;
#pragma unroll
      for (int o = 0; o < 6; ++o) orow[o] = p[o];
    }
  }
}

extern "C" void kernel_launch(void* const* d_in, const int* in_sizes, int n_in,
                              void* d_out, int out_size, void* d_ws, size_t ws_size,
                              hipStream_t stream) {
  const int* h = (const int*)d_in[0];
  const int* src = (const int*)d_in[1];
  const int* dst = (const int*)d_in[2];
  const float* emb = (const float*)d_in[3];
  const float* W = (const float*)d_in[4];
  const float* b = (const float*)d_in[5];
  const float* gamma = (const float*)d_in[6];
  const float* beta = (const float*)d_in[7];
  const float* W1 = (const float*)d_in[8];
  const float* b1 = (const float*)d_in[9];
  const float* W2 = (const float*)d_in[10];
  const float* b2 = (const float*)d_in[11];
  const float* W3 = (const float*)d_in[12];
  const float* b3 = (const float*)d_in[13];
  float* out = (float*)d_out;

  char* ws = (char*)d_ws;
  size_t off = 0;
  auto alloc = [&](size_t bytes) -> void* {
    void* p = ws + off;
    off += (bytes + 255) & ~(size_t)255;
    return p;
  };
  int* deg_out = (int*)alloc(N_NODES * 4);
  float* norm_src = (float*)alloc(N_NODES * 4);
  float* norm_dst = (float*)alloc(N_NODES * 4);
  int* row_ptr = (int*)alloc((N_NODES + 1) * 4);
  int* csr_src = (int*)alloc((size_t)N_EDGES * 4);
  int* bucket_cnt = (int*)alloc(NBUCK * 4);
  int* bucket_base = (int*)alloc((NBUCK + 1) * 4);
  int* bucket_fill = (int*)alloc(NBUCK * 4);
  float* x = (float*)alloc((size_t)N_NODES * HID * 4);
  unsigned short* xb = (unsigned short*)alloc((size_t)N_NODES * HID * 2);
  unsigned short* agg_hi = (unsigned short*)alloc((size_t)N_NODES * HID * 2);
  unsigned short* agg_lo = (unsigned short*)alloc((size_t)N_NODES * HID * 2);
  float* Yb = (float*)alloc((size_t)N_NODES * HID * 4);
  unsigned short* Wh = (unsigned short*)alloc((size_t)N_LAYERS * HID * HID * 2);
  unsigned short* Wl = (unsigned short*)alloc((size_t)N_LAYERS * HID * HID * 2);
  unsigned short* B1h = (unsigned short*)alloc(64 * 128 * 2);
  unsigned short* B1l = (unsigned short*)alloc(64 * 128 * 2);
  unsigned short* B2h = (unsigned short*)alloc(32 * 64 * 2);
  unsigned short* B2l = (unsigned short*)alloc(32 * 64 * 2);
  float* sums = (float*)alloc(512);
  float* sumsq = (float*)alloc(512);
  float* scale = (float*)alloc(512);
  float* shift = (float*)alloc(512);
  int2* pairs = (int2*)Yb;  // overlay: pairs (12.8MB) dead before Yb first written (layer-1 gemm)

  hipMemsetAsync(deg_out, 0, N_NODES * 4, stream);
  hipMemsetAsync(bucket_cnt, 0, NBUCK * 4, stream);
  k_hist<<<256, 256, 0, stream>>>(src, dst, bucket_cnt, deg_out);
  k_bscan<<<1, 256, 0, stream>>>(bucket_cnt, bucket_base, bucket_fill);
  k_scatter2<<<(N_EDGES + CBLK - 1) / CBLK, 256, 0, stream>>>(src, dst, bucket_base, bucket_fill, pairs);
  k_bucket_csr<<<NBUCK, 256, 0, stream>>>(pairs, bucket_base, row_ptr, norm_dst, csr_src);
  k_norms_src<<<(N_NODES + 255) / 256, 256, 0, stream>>>(deg_out, norm_src);
  k_embed<<<(N_NODES * (HID / 4) + 255) / 256, 256, 0, stream>>>(h, emb, norm_src, x, xb);
  k_wsplit<<<N_LAYERS * 128, 128, 0, stream>>>(W, Wh, Wl);
  k_wsplit_t<<<(128 * 64 + 255) / 256, 256, 0, stream>>>(W1, B1h, B1l, 128, 64);
  k_wsplit_t<<<(64 * 32 + 255) / 256, 256, 0, stream>>>(W2, B2h, B2l, 64, 32);

  for (int l = 0; l < N_LAYERS; ++l) {
    k_agg<<<(N_NODES + 15) / 16, 256, 0, stream>>>(xb, row_ptr, csr_src, norm_dst, agg_hi, agg_lo);
    hipMemsetAsync(sums, 0, 1024, stream);  // sums+sumsq contiguous
    k_gemm_mfma<<<(N_NODES + 127) / 128, 256, 0, stream>>>(agg_hi, agg_lo,
                                                           Wh + (size_t)l * HID * HID, Wl + (size_t)l * HID * HID,
                                                           b + l * HID, Yb, sums, sumsq);
    k_bn_final<<<1, 128, 0, stream>>>(sums, sumsq, gamma + l * HID, beta + l * HID, scale, shift);
    if (l < N_LAYERS - 1) {
      k_bn_apply<<<(N_NODES * (HID / 4) + 255) / 256, 256, 0, stream>>>(Yb, scale, shift, norm_src, x, xb);
    }
  }
  k_readout<<<(N_NODES + 127) / 128, 256, 0, stream>>>(Yb, x, scale, shift,
                                                       B1h, B1l, b1, B2h, B2l, b2, W3, b3, out);
}